// Round 7
// baseline (544.600 us; speedup 1.0000x reference)
//
#include <hip/hip_runtime.h>

#define N_NODES 100000
#define FOUT 64

// partitioned-build constants
#define PSHIFT 11
#define PSIZE  2048
#define NPART  ((N_NODES + PSIZE - 1) / PSIZE)   // 49
#define TILE   8192
#define SRCBITS 17
#define SRCMASK 0x1FFFF

#define SCAN_BLOCK 256
#define SCAN_ITEMS 8
#define SCAN_ELEMS (SCAN_BLOCK * SCAN_ITEMS)

// ---------------- bf16 helpers (manual, RNE) ----------------

static __device__ __forceinline__ float bf2f(unsigned short u) {
    union { unsigned int i; float f; } v;
    v.i = (unsigned int)u << 16;
    return v.f;
}
static __device__ __forceinline__ unsigned short f2bf(float f) {
    union { float f; unsigned int i; } v;
    v.f = f;
    unsigned int r = (v.i + 0x7fffu + ((v.i >> 16) & 1u)) >> 16;
    return (unsigned short)r;
}
static __device__ __forceinline__ float2 up2(unsigned int u) {
    float2 r;
    r.x = bf2f((unsigned short)(u & 0xffffu));
    r.y = bf2f((unsigned short)(u >> 16));
    return r;
}
static __device__ __forceinline__ unsigned int pk2(float x, float y) {
    return (unsigned int)f2bf(x) | ((unsigned int)f2bf(y) << 16);
}

template <typename T> static __device__ __forceinline__ float ldf(const T* p);
template <> __device__ __forceinline__ float ldf<float>(const float* p) { return *p; }
template <> __device__ __forceinline__ float ldf<unsigned short>(const unsigned short* p) { return bf2f(*p); }

static __device__ __forceinline__ void st2(float* base, int idx, float2 v) {
    ((float2*)base)[idx] = v;
}
static __device__ __forceinline__ void st2(unsigned short* base, int idx, float2 v) {
    ((unsigned int*)base)[idx] = pk2(v.x, v.y);
}

// ---------------- utility ----------------

// zero partition counters + write ids output (grid 4 x 256)
__global__ void k_init(int* __restrict__ dstCnt, int* __restrict__ srcCnt,
                       const int* __restrict__ ids, float* __restrict__ outid, int nid) {
    int i = blockIdx.x * blockDim.x + threadIdx.x;
    if (i < NPART) { dstCnt[i] = 0; srcCnt[i] = 0; }
    if (i < nid) outid[i] = (float)ids[i];
}

// ---------------- partitioned build (replaces 4.8M random RMW @ ~28G/s wall) ----------------

// phase 1a: per-tile LDS histograms -> 49 hot global atomics per tile
__global__ void k_count(const int* __restrict__ src, const int* __restrict__ dst,
                        int* __restrict__ dstCnt, int* __restrict__ srcCnt, int E) {
    __shared__ int dh[NPART];
    __shared__ int sh2[NPART];
    const int tid = threadIdx.x;
    const int base = blockIdx.x * TILE;
    const int end = min(base + TILE, E);
    if (tid < NPART) { dh[tid] = 0; sh2[tid] = 0; }
    __syncthreads();
    for (int j = base + tid; j < end; j += 256) {
        atomicAdd(&dh[dst[j] >> PSHIFT], 1);
        atomicAdd(&sh2[src[j] >> PSHIFT], 1);
    }
    __syncthreads();
    if (tid < NPART) {
        if (dh[tid])  atomicAdd(&dstCnt[tid], dh[tid]);
        if (sh2[tid]) atomicAdd(&srcCnt[tid], sh2[tid]);
    }
}

// phase 1b: exclusive scan of 49 partition counts (one wave each) -> bases + cursors
__global__ void k_scan_parts(const int* __restrict__ dstCnt, const int* __restrict__ srcCnt,
                             int* __restrict__ partBaseD, int* __restrict__ partBaseS,
                             int* __restrict__ dstCur, int* __restrict__ srcCur) {
    const int tid = threadIdx.x;
    if (tid < 64) {
        int lane = tid;
        int v = (lane < NPART) ? dstCnt[lane] : 0;
        int x = v;
        for (int off = 1; off < 64; off <<= 1) {
            int y = __shfl_up(x, off);
            if (lane >= off) x += y;
        }
        if (lane < NPART) {
            partBaseD[lane] = x - v;
            dstCur[lane]    = x - v;
            if (lane == NPART - 1) partBaseD[NPART] = x;
        }
    } else if (tid < 128) {
        int lane = tid - 64;
        int v = (lane < NPART) ? srcCnt[lane] : 0;
        int x = v;
        for (int off = 1; off < 64; off <<= 1) {
            int y = __shfl_up(x, off);
            if (lane >= off) x += y;
        }
        if (lane < NPART) {
            partBaseS[lane] = x - v;
            srcCur[lane]    = x - v;
            if (lane == NPART - 1) partBaseS[NPART] = x;
        }
    }
}

// phase 1c: per-tile LDS scatter into bin-contiguous staging, coalesced run flush.
// dstStream record: (dstLocal<<17)|src (28 bits). srcStream record: srcLocal (ushort).
__global__ void k_binscatter(const int* __restrict__ src, const int* __restrict__ dst,
                             int* __restrict__ dstCur, int* __restrict__ srcCur,
                             unsigned int* __restrict__ dstStream,
                             unsigned short* __restrict__ srcStream, int E) {
    __shared__ unsigned int   stageD[TILE];    // 32 KB
    __shared__ unsigned short stageS[TILE];    // 16 KB
    __shared__ int dh[NPART], sh2[NPART];
    __shared__ int dLoc[NPART], sLoc[NPART];
    __shared__ int dBase[NPART], sBase[NPART];
    __shared__ int dFence[NPART + 1], sFence[NPART + 1];
    __shared__ int dcur[NPART], scur[NPART];

    const int tid = threadIdx.x;
    const int base = blockIdx.x * TILE;
    const int end = min(base + TILE, E);
    const int n = end - base;

    if (tid < NPART) { dh[tid] = 0; sh2[tid] = 0; }
    __syncthreads();

    // pass A: local histograms
    for (int j = base + tid; j < end; j += 256) {
        atomicAdd(&dh[dst[j] >> PSHIFT], 1);
        atomicAdd(&sh2[src[j] >> PSHIFT], 1);
    }
    __syncthreads();

    // wave 0: scan dst hist + reserve global runs; wave 1: src
    if (tid < 64) {
        int lane = tid;
        int v = (lane < NPART) ? dh[lane] : 0;
        int x = v;
        for (int off = 1; off < 64; off <<= 1) {
            int y = __shfl_up(x, off);
            if (lane >= off) x += y;
        }
        if (lane < NPART) {
            dLoc[lane] = x - v;
            dcur[lane] = x - v;
            dFence[lane + 1] = x;
            dBase[lane] = v ? atomicAdd(&dstCur[lane], v) : 0;
        }
        if (lane == 0) dFence[0] = 0;
    } else if (tid < 128) {
        int lane = tid - 64;
        int v = (lane < NPART) ? sh2[lane] : 0;
        int x = v;
        for (int off = 1; off < 64; off <<= 1) {
            int y = __shfl_up(x, off);
            if (lane >= off) x += y;
        }
        if (lane < NPART) {
            sLoc[lane] = x - v;
            scur[lane] = x - v;
            sFence[lane + 1] = x;
            sBase[lane] = v ? atomicAdd(&srcCur[lane], v) : 0;
        }
        if (lane == 0) sFence[0] = 0;
    }
    __syncthreads();

    // pass B: scatter into staging (bin-contiguous)
    for (int j = base + tid; j < end; j += 256) {
        int s = src[j], d = dst[j];
        int db = d >> PSHIFT;
        int sb = s >> PSHIFT;
        int pd = atomicAdd(&dcur[db], 1);
        stageD[pd] = ((unsigned int)(d & (PSIZE - 1)) << SRCBITS) | (unsigned int)s;
        int ps = atomicAdd(&scur[sb], 1);
        stageS[ps] = (unsigned short)(s & (PSIZE - 1));
    }
    __syncthreads();

    // flush: staged order is bin-contiguous -> coalesced runs
    for (int j = tid; j < n; j += 256) {
        // find dst bin: largest b with dFence[b] <= j
        int lo = 0, hi = NPART;
        while (hi - lo > 1) { int mid = (lo + hi) >> 1; if (dFence[mid] <= j) lo = mid; else hi = mid; }
        dstStream[dBase[lo] + (j - dLoc[lo])] = stageD[j];
        lo = 0; hi = NPART;
        while (hi - lo > 1) { int mid = (lo + hi) >> 1; if (sFence[mid] <= j) lo = mid; else hi = mid; }
        srcStream[sBase[lo] + (j - sLoc[lo])] = stageS[j];
    }
}

// phase 2a: per-dst-partition counting sort -> row_off + csr_src (no global atomics)
__global__ void k_csr(const unsigned int* __restrict__ dstStream,
                      const int* __restrict__ partBaseD,
                      int* __restrict__ row_off, int* __restrict__ csr_src) {
    __shared__ int hist[PSIZE];   // 8 KB
    __shared__ int part[256];
    const int tid = threadIdx.x;
    const int p = blockIdx.x;
    const int nodeBase = p << PSHIFT;
    const int nN = min(PSIZE, N_NODES - nodeBase);
    const int e0 = partBaseD[p];
    const int e1 = partBaseD[p + 1];

    for (int i = tid; i < PSIZE; i += 256) hist[i] = 0;
    __syncthreads();
    for (int e = e0 + tid; e < e1; e += 256)
        atomicAdd(&hist[dstStream[e] >> SRCBITS], 1);
    __syncthreads();

    // block scan of 2048: 8/thread serial + 256-wide block scan
    const int bi = tid * 8;
    int my[8]; int s = 0;
#pragma unroll
    for (int k = 0; k < 8; k++) { my[k] = hist[bi + k]; s += my[k]; }
    part[tid] = s;
    __syncthreads();
    for (int off = 1; off < 256; off <<= 1) {
        int v = (tid >= off) ? part[tid - off] : 0;
        __syncthreads();
        part[tid] += v;
        __syncthreads();
    }
    int run = (tid == 0) ? 0 : part[tid - 1];
#pragma unroll
    for (int k = 0; k < 8; k++) {
        int c = my[k];
        hist[bi + k] = run;                       // exclusive offset -> cursor
        int node = bi + k;
        if (node < nN) row_off[nodeBase + node] = e0 + run;
        run += c;
    }
    if (p == NPART - 1 && tid == 0) row_off[N_NODES] = e1;
    __syncthreads();

    // scatter: writes stay within this partition's contiguous span (L2-coalesced)
    for (int e = e0 + tid; e < e1; e += 256) {
        unsigned int rec = dstStream[e];
        int d = rec >> SRCBITS;
        int sv = rec & SRCMASK;
        int pos = atomicAdd(&hist[d], 1);
        csr_src[e0 + pos] = sv;
    }
}

// phase 2b: per-src-partition histogram -> out_deg (no global atomics)
__global__ void k_odeg(const unsigned short* __restrict__ srcStream,
                       const int* __restrict__ partBaseS, int* __restrict__ out_deg) {
    __shared__ int hist[PSIZE];
    const int tid = threadIdx.x;
    const int p = blockIdx.x;
    const int nodeBase = p << PSHIFT;
    const int nN = min(PSIZE, N_NODES - nodeBase);
    const int e0 = partBaseS[p];
    const int e1 = partBaseS[p + 1];

    for (int i = tid; i < PSIZE; i += 256) hist[i] = 0;
    __syncthreads();
    for (int e = e0 + tid; e < e1; e += 256)
        atomicAdd(&hist[srcStream[e]], 1);
    __syncthreads();
    for (int i = tid; i < nN; i += 256) out_deg[nodeBase + i] = hist[i];
}

// ---------------- CSR fallback path (fp32, used only if ws too small) ----------------

__global__ void k_init_fb(int* __restrict__ a, int* __restrict__ b,
                          const int* __restrict__ ids, float* __restrict__ outid,
                          int n, int nid) {
    int i = blockIdx.x * blockDim.x + threadIdx.x;
    if (i < n) { a[i] = 0; b[i] = 0; }
    if (i < nid) outid[i] = (float)ids[i];
}

__global__ void k_histo(const int* __restrict__ src, const int* __restrict__ dst,
                        int* __restrict__ out_deg, int* __restrict__ in_deg, int n) {
    int i = blockIdx.x * blockDim.x + threadIdx.x;
    if (i < n) {
        atomicAdd(&out_deg[src[i]], 1);
        atomicAdd(&in_deg[dst[i]], 1);
    }
}

__global__ void k_scan_partial(const int* __restrict__ deg, int* __restrict__ block_sums, int n) {
    __shared__ int red[SCAN_BLOCK];
    const int t = threadIdx.x;
    const int base = blockIdx.x * SCAN_ELEMS + t * SCAN_ITEMS;
    int s = 0;
#pragma unroll
    for (int k = 0; k < SCAN_ITEMS; k++) {
        int i = base + k;
        if (i < n) s += deg[i];
    }
    red[t] = s;
    __syncthreads();
    for (int off = SCAN_BLOCK / 2; off > 0; off >>= 1) {
        if (t < off) red[t] += red[t + off];
        __syncthreads();
    }
    if (t == 0) block_sums[blockIdx.x] = red[0];
}

__global__ void k_scan_blocks(int* __restrict__ block_sums, int nb) {
    __shared__ int sh[SCAN_BLOCK];
    const int t = threadIdx.x;
    sh[t] = (t < nb) ? block_sums[t] : 0;
    __syncthreads();
    for (int off = 1; off < SCAN_BLOCK; off <<= 1) {
        int v = (t >= off) ? sh[t - off] : 0;
        __syncthreads();
        sh[t] += v;
        __syncthreads();
    }
    if (t < nb) block_sums[t] = (t == 0) ? 0 : sh[t - 1];
}

__global__ void k_scan_write(const int* __restrict__ deg, const int* __restrict__ block_off,
                             int* __restrict__ row_off, int* __restrict__ cursor, int n) {
    __shared__ int sh[SCAN_BLOCK];
    const int t = threadIdx.x;
    const int base = blockIdx.x * SCAN_ELEMS + t * SCAN_ITEMS;
    int v[SCAN_ITEMS];
    int s = 0;
#pragma unroll
    for (int k = 0; k < SCAN_ITEMS; k++) {
        int i = base + k;
        v[k] = (i < n) ? deg[i] : 0;
        s += v[k];
    }
    sh[t] = s;
    __syncthreads();
    for (int off = 1; off < SCAN_BLOCK; off <<= 1) {
        int x = (t >= off) ? sh[t - off] : 0;
        __syncthreads();
        sh[t] += x;
        __syncthreads();
    }
    int run = block_off[blockIdx.x] + ((t == 0) ? 0 : sh[t - 1]);
#pragma unroll
    for (int k = 0; k < SCAN_ITEMS; k++) {
        int i = base + k;
        if (i < n) { row_off[i] = run; cursor[i] = run; run += v[k]; }
    }
    if (blockIdx.x == gridDim.x - 1 && t == SCAN_BLOCK - 1) {
        row_off[n] = block_off[blockIdx.x] + sh[SCAN_BLOCK - 1];
    }
}

__global__ void k_scatter(const int* __restrict__ src, const int* __restrict__ dst,
                          int* __restrict__ cursor, int* __restrict__ csr_src, int n) {
    int i = blockIdx.x * blockDim.x + threadIdx.x;
    if (i < n) {
        int d = dst[i];
        int pos = atomicAdd(&cursor[d], 1);
        csr_src[pos] = src[i];
    }
}

// ---------------- layer kernels ----------------

// t[node][j] = sum_k (h[node][k] * rsqrt(out_deg[node]+1)) * W[k][j]
template <int FIN, typename TIN, typename TOUT>
__global__ void k_gemm(const TIN* __restrict__ h, const int* __restrict__ out_deg,
                       const float* __restrict__ W, TOUT* __restrict__ t) {
    __shared__ float sh[32 * FIN];
    __shared__ float sno[32];
    const int tid = threadIdx.x;
    const int block0 = blockIdx.x * 32;

    if (tid < 32) sno[tid] = rsqrtf((float)(out_deg[block0 + tid] + 1));
    __syncthreads();

    for (int idx = tid; idx < 32 * FIN; idx += 256) {
        int r = idx / FIN;
        int c = idx % FIN;
        sh[idx] = ldf(&h[(size_t)(block0 + r) * FIN + c]) * sno[r];
    }
    __syncthreads();

    const int j2 = tid & 31;
    const int rg = tid >> 5;
    const float2* W2 = (const float2*)W;
    float2 a0 = {0.f, 0.f}, a1 = {0.f, 0.f}, a2 = {0.f, 0.f}, a3 = {0.f, 0.f};
#pragma unroll 4
    for (int k = 0; k < FIN; k++) {
        float2 w = W2[k * 32 + j2];
        float s0 = sh[(rg + 0)  * FIN + k];
        float s1 = sh[(rg + 8)  * FIN + k];
        float s2 = sh[(rg + 16) * FIN + k];
        float s3 = sh[(rg + 24) * FIN + k];
        a0.x += s0 * w.x; a0.y += s0 * w.y;
        a1.x += s1 * w.x; a1.y += s1 * w.y;
        a2.x += s2 * w.x; a2.y += s2 * w.y;
        a3.x += s3 * w.x; a3.y += s3 * w.y;
    }
    TOUT* tp = t + (size_t)block0 * FOUT;
    st2(tp, (rg + 0)  * 32 + j2, a0);
    st2(tp, (rg + 8)  * 32 + j2, a1);
    st2(tp, (rg + 16) * 32 + j2, a2);
    st2(tp, (rg + 24) * 32 + j2, a3);
}

// CSR SpMM, bf16 rows: one wave per dst node, two rows per 256B wave-load
template <typename TOUT>
__global__ void k_spmm_b(const unsigned int* __restrict__ t2,  // bf16x2 rows, pitch 32
                         const int* __restrict__ row_off, const int* __restrict__ csr_src,
                         const float* __restrict__ bias, TOUT* __restrict__ out) {
    const int wave = blockIdx.x * (blockDim.x >> 6) + (threadIdx.x >> 6);
    const int lane = threadIdx.x & 63;
    const int pair = lane >> 5;
    const int c    = lane & 31;
    const int d = wave;
    const int e0 = row_off[d];
    const int deg = row_off[d + 1] - e0;
    const float inorm = rsqrtf((float)(deg + 1));
    const int* bk = csr_src + e0;

    float2 a0 = {0.f, 0.f}, a1 = {0.f, 0.f}, a2 = {0.f, 0.f}, a3 = {0.f, 0.f};
    float2 a4 = {0.f, 0.f}, a5 = {0.f, 0.f}, a6 = {0.f, 0.f}, a7 = {0.f, 0.f};

    if (pair == 0) {                          // self loop (half 0 only)
        float2 v = up2(t2[(size_t)d * 32 + c]);
        a0.x += v.x; a0.y += v.y;
    }

    int e = 0;
    for (; e + 16 <= deg; e += 16) {
        int s0 = bk[e + 0  + pair], s1 = bk[e + 2  + pair];
        int s2 = bk[e + 4  + pair], s3 = bk[e + 6  + pair];
        int s4 = bk[e + 8  + pair], s5 = bk[e + 10 + pair];
        int s6 = bk[e + 12 + pair], s7 = bk[e + 14 + pair];
        unsigned int v0 = t2[(size_t)s0 * 32 + c];
        unsigned int v1 = t2[(size_t)s1 * 32 + c];
        unsigned int v2 = t2[(size_t)s2 * 32 + c];
        unsigned int v3 = t2[(size_t)s3 * 32 + c];
        unsigned int v4 = t2[(size_t)s4 * 32 + c];
        unsigned int v5 = t2[(size_t)s5 * 32 + c];
        unsigned int v6 = t2[(size_t)s6 * 32 + c];
        unsigned int v7 = t2[(size_t)s7 * 32 + c];
        float2 f;
        f = up2(v0); a0.x += f.x; a0.y += f.y;
        f = up2(v1); a1.x += f.x; a1.y += f.y;
        f = up2(v2); a2.x += f.x; a2.y += f.y;
        f = up2(v3); a3.x += f.x; a3.y += f.y;
        f = up2(v4); a4.x += f.x; a4.y += f.y;
        f = up2(v5); a5.x += f.x; a5.y += f.y;
        f = up2(v6); a6.x += f.x; a6.y += f.y;
        f = up2(v7); a7.x += f.x; a7.y += f.y;
    }
    for (; e + 8 <= deg; e += 8) {
        int s0 = bk[e + 0 + pair], s1 = bk[e + 2 + pair];
        int s2 = bk[e + 4 + pair], s3 = bk[e + 6 + pair];
        unsigned int v0 = t2[(size_t)s0 * 32 + c];
        unsigned int v1 = t2[(size_t)s1 * 32 + c];
        unsigned int v2 = t2[(size_t)s2 * 32 + c];
        unsigned int v3 = t2[(size_t)s3 * 32 + c];
        float2 f;
        f = up2(v0); a0.x += f.x; a0.y += f.y;
        f = up2(v1); a1.x += f.x; a1.y += f.y;
        f = up2(v2); a2.x += f.x; a2.y += f.y;
        f = up2(v3); a3.x += f.x; a3.y += f.y;
    }
    for (; e + 4 <= deg; e += 4) {
        int s0 = bk[e + 0 + pair], s1 = bk[e + 2 + pair];
        unsigned int v0 = t2[(size_t)s0 * 32 + c];
        unsigned int v1 = t2[(size_t)s1 * 32 + c];
        float2 f;
        f = up2(v0); a0.x += f.x; a0.y += f.y;
        f = up2(v1); a1.x += f.x; a1.y += f.y;
    }
    for (; e + 2 <= deg; e += 2) {
        int s0 = bk[e + pair];
        float2 f = up2(t2[(size_t)s0 * 32 + c]);
        a0.x += f.x; a0.y += f.y;
    }
    if (e < deg && pair == 0) {
        float2 f = up2(t2[(size_t)bk[e] * 32 + c]);
        a0.x += f.x; a0.y += f.y;
    }

    float2 tot;
    tot.x = ((a0.x + a1.x) + (a2.x + a3.x)) + ((a4.x + a5.x) + (a6.x + a7.x));
    tot.y = ((a0.y + a1.y) + (a2.y + a3.y)) + ((a4.y + a5.y) + (a6.y + a7.y));
    tot.x += __shfl_xor(tot.x, 32);
    tot.y += __shfl_xor(tot.y, 32);

    if (pair == 0) {
        float2 bb = *(const float2*)(bias + 2 * c);
        float2 r;
        r.x = inorm * tot.x + bb.x;
        r.y = inorm * tot.y + bb.y;
        st2(out, (int)((size_t)d * 32 + c), r);
    }
}

// fp32 CSR SpMM (fallback)
__global__ void k_spmm_c(const float* __restrict__ t, const int* __restrict__ row_off,
                         const int* __restrict__ csr_src, const float* __restrict__ bias,
                         float* __restrict__ out) {
    const int wave = blockIdx.x * (blockDim.x >> 6) + (threadIdx.x >> 6);
    const int lane = threadIdx.x & 63;
    const int d = wave;
    const int e0 = row_off[d];
    const int e1 = row_off[d + 1];
    const float inorm = rsqrtf((float)(e1 - e0 + 1));

    float a0 = t[(size_t)d * FOUT + lane];
    float a1 = 0.f, a2 = 0.f, a3 = 0.f, a4 = 0.f, a5 = 0.f, a6 = 0.f, a7 = 0.f;
    int e = e0;
    for (; e + 8 <= e1; e += 8) {
        int s0 = csr_src[e + 0], s1 = csr_src[e + 1], s2 = csr_src[e + 2], s3 = csr_src[e + 3];
        int s4 = csr_src[e + 4], s5 = csr_src[e + 5], s6 = csr_src[e + 6], s7 = csr_src[e + 7];
        a0 += t[(size_t)s0 * FOUT + lane];
        a1 += t[(size_t)s1 * FOUT + lane];
        a2 += t[(size_t)s2 * FOUT + lane];
        a3 += t[(size_t)s3 * FOUT + lane];
        a4 += t[(size_t)s4 * FOUT + lane];
        a5 += t[(size_t)s5 * FOUT + lane];
        a6 += t[(size_t)s6 * FOUT + lane];
        a7 += t[(size_t)s7 * FOUT + lane];
    }
    for (; e + 4 <= e1; e += 4) {
        int s0 = csr_src[e + 0], s1 = csr_src[e + 1], s2 = csr_src[e + 2], s3 = csr_src[e + 3];
        a0 += t[(size_t)s0 * FOUT + lane];
        a1 += t[(size_t)s1 * FOUT + lane];
        a2 += t[(size_t)s2 * FOUT + lane];
        a3 += t[(size_t)s3 * FOUT + lane];
    }
    for (; e < e1; e++) a0 += t[(size_t)csr_src[e] * FOUT + lane];

    float acc = ((a0 + a1) + (a2 + a3)) + ((a4 + a5) + (a6 + a7));
    out[(size_t)d * FOUT + lane] = inorm * acc + bias[lane];
}

// ---------------- launch ----------------

extern "C" void kernel_launch(void* const* d_in, const int* in_sizes, int n_in,
                              void* d_out, int out_size, void* d_ws, size_t ws_size,
                              hipStream_t stream) {
    const float* h   = (const float*)d_in[0];
    const int*   src = (const int*)d_in[1];
    const int*   dst = (const int*)d_in[2];
    const int*   ids = (const int*)d_in[3];
    const float* W0  = (const float*)d_in[4];
    const float* b0  = (const float*)d_in[5];
    const float* W1  = (const float*)d_in[6];
    const float* b1  = (const float*)d_in[7];
    const float* W2  = (const float*)d_in[8];
    const float* b2  = (const float*)d_in[9];
    const int N = N_NODES;
    const int E = in_sizes[1];

    size_t o = 0;
    auto alloc = [&](size_t nbytes) -> void* {
        void* p = (char*)d_ws + o;
        o += (nbytes + 255) & ~(size_t)255;
        return p;
    };

    float* outp = (float*)d_out;
    const int B = 256;
    const int gemmGrid = N / 32;   // 3125
    const int spmmGrid = N / 4;    // 25000 blocks x 4 waves

    // new path: dstStream(4E) + srcStream(2E) + csr_src(4E) + row_off + out_deg
    //           + small counters + 2 bf16 feature buffers  ~= 42.5 MB
    const size_t needNew =
        (((size_t)E * 4 + 255) & ~(size_t)255) +
        (((size_t)E * 2 + 255) & ~(size_t)255) +
        (((size_t)E * 4 + 255) & ~(size_t)255) +
        (((size_t)(N + 1) * 4 + 255) & ~(size_t)255) +
        (((size_t)N * 4 + 255) & ~(size_t)255) +
        6 * 512 +
        2 * (((size_t)N * FOUT * 2 + 255) & ~(size_t)255) + 4096;

    if (ws_size >= needNew) {
        // ---------- partitioned-sort build + bf16 layers ----------
        unsigned int*   dstStream = (unsigned int*)alloc((size_t)E * 4);
        unsigned short* srcStream = (unsigned short*)alloc((size_t)E * 2);
        int*            csr_src   = (int*)alloc((size_t)E * 4);
        int*            row_off   = (int*)alloc((size_t)(N + 1) * 4);
        int*            out_deg   = (int*)alloc((size_t)N * 4);
        int*            dstCnt    = (int*)alloc(512);
        int*            srcCnt    = (int*)alloc(512);
        int*            dstCur    = (int*)alloc(512);
        int*            srcCur    = (int*)alloc(512);
        int*            partBaseD = (int*)alloc(512);
        int*            partBaseS = (int*)alloc(512);
        unsigned short* t         = (unsigned short*)alloc((size_t)N * FOUT * 2);
        unsigned short* hbuf      = (unsigned short*)alloc((size_t)N * FOUT * 2);

        const int nTiles = (E + TILE - 1) / TILE;   // 196

        k_init<<<4, B, 0, stream>>>(dstCnt, srcCnt, ids, outp + (size_t)N * FOUT, 1024);
        k_count<<<nTiles, B, 0, stream>>>(src, dst, dstCnt, srcCnt, E);
        k_scan_parts<<<1, 128, 0, stream>>>(dstCnt, srcCnt, partBaseD, partBaseS, dstCur, srcCur);
        k_binscatter<<<nTiles, B, 0, stream>>>(src, dst, dstCur, srcCur, dstStream, srcStream, E);
        k_csr<<<NPART, B, 0, stream>>>(dstStream, partBaseD, row_off, csr_src);
        k_odeg<<<NPART, B, 0, stream>>>(srcStream, partBaseS, out_deg);

        // layer 0: 128 -> 64 (fp32 in, bf16 out)
        k_gemm<128, float, unsigned short><<<gemmGrid, 256, 0, stream>>>(h, out_deg, W0, t);
        k_spmm_b<unsigned short><<<spmmGrid, 256, 0, stream>>>((const unsigned int*)t, row_off, csr_src, b0, hbuf);
        // layer 1
        k_gemm<64, unsigned short, unsigned short><<<gemmGrid, 256, 0, stream>>>(hbuf, out_deg, W1, t);
        k_spmm_b<unsigned short><<<spmmGrid, 256, 0, stream>>>((const unsigned int*)t, row_off, csr_src, b1, hbuf);
        // layer 2 (fp32 final out)
        k_gemm<64, unsigned short, unsigned short><<<gemmGrid, 256, 0, stream>>>(hbuf, out_deg, W2, t);
        k_spmm_b<float><<<spmmGrid, 256, 0, stream>>>((const unsigned int*)t, row_off, csr_src, b2, outp);
    } else {
        // ---------- CSR fallback (fp32, atomic build) ----------
        int*   in_deg  = (int*)alloc((size_t)N * 4);
        int*   out_deg = (int*)alloc((size_t)N * 4);
        int*   row_off = (int*)alloc((size_t)(N + 1) * 4);
        int*   cursor  = (int*)alloc((size_t)N * 4);
        int*   csr_src = (int*)alloc((size_t)E * 4);
        float* t       = (float*)alloc((size_t)N * FOUT * 4);
        float* hbuf    = (float*)alloc((size_t)N * FOUT * 4);
        int*   bsums   = (int*)alloc((size_t)SCAN_BLOCK * 4);

        const int gN = (N + B - 1) / B;
        const int gE = (E + B - 1) / B;
        const int nScanBlocks = (N + SCAN_ELEMS - 1) / SCAN_ELEMS;

        k_init_fb<<<gN, B, 0, stream>>>(in_deg, out_deg, ids, outp + (size_t)N * FOUT, N, 1024);
        k_histo<<<gE, B, 0, stream>>>(src, dst, out_deg, in_deg, E);
        k_scan_partial<<<nScanBlocks, SCAN_BLOCK, 0, stream>>>(in_deg, bsums, N);
        k_scan_blocks<<<1, SCAN_BLOCK, 0, stream>>>(bsums, nScanBlocks);
        k_scan_write<<<nScanBlocks, SCAN_BLOCK, 0, stream>>>(in_deg, bsums, row_off, cursor, N);
        k_scatter<<<gE, B, 0, stream>>>(src, dst, cursor, csr_src, E);

        k_gemm<128, float, float><<<N / 32, 256, 0, stream>>>(h, out_deg, W0, t);
        k_spmm_c<<<spmmGrid, 256, 0, stream>>>(t, row_off, csr_src, b0, hbuf);
        k_gemm<64, float, float><<<N / 32, 256, 0, stream>>>(hbuf, out_deg, W1, t);
        k_spmm_c<<<spmmGrid, 256, 0, stream>>>(t, row_off, csr_src, b1, hbuf);
        k_gemm<64, float, float><<<N / 32, 256, 0, stream>>>(hbuf, out_deg, W2, t);
        k_spmm_c<<<spmmGrid, 256, 0, stream>>>(t, row_off, csr_src, b2, outp);
    }
}

// Round 8
// 424.713 us; speedup vs baseline: 1.2823x; 1.2823x over previous
//
#include <hip/hip_runtime.h>

#define N_NODES 100000
#define FOUT 64

// partitioned-build constants
#define PSHIFT 9
#define PSIZE  512
#define NPART  ((N_NODES + PSIZE - 1) / PSIZE)   // 196
#define TILE   8192
#define SRCBITS 17
#define SRCMASK 0x1FFFF

#define SCAN_BLOCK 256
#define SCAN_ITEMS 8
#define SCAN_ELEMS (SCAN_BLOCK * SCAN_ITEMS)

typedef __attribute__((ext_vector_type(8))) short bf16x8;
typedef __attribute__((ext_vector_type(4))) float f32x4;

// ---------------- bf16 helpers (manual, RNE) ----------------

static __device__ __forceinline__ float bf2f(unsigned short u) {
    union { unsigned int i; float f; } v;
    v.i = (unsigned int)u << 16;
    return v.f;
}
static __device__ __forceinline__ unsigned short f2bf(float f) {
    union { float f; unsigned int i; } v;
    v.f = f;
    unsigned int r = (v.i + 0x7fffu + ((v.i >> 16) & 1u)) >> 16;
    return (unsigned short)r;
}
static __device__ __forceinline__ float2 up2(unsigned int u) {
    float2 r;
    r.x = bf2f((unsigned short)(u & 0xffffu));
    r.y = bf2f((unsigned short)(u >> 16));
    return r;
}
static __device__ __forceinline__ unsigned int pk2(float x, float y) {
    return (unsigned int)f2bf(x) | ((unsigned int)f2bf(y) << 16);
}

template <typename T> static __device__ __forceinline__ float ldf(const T* p);
template <> __device__ __forceinline__ float ldf<float>(const float* p) { return *p; }
template <> __device__ __forceinline__ float ldf<unsigned short>(const unsigned short* p) { return bf2f(*p); }

template <typename T> static __device__ __forceinline__ void stf(T* p, float v);
template <> __device__ __forceinline__ void stf<float>(float* p, float v) { *p = v; }
template <> __device__ __forceinline__ void stf<unsigned short>(unsigned short* p, float v) { *p = f2bf(v); }

static __device__ __forceinline__ void st2(float* base, int idx, float2 v) {
    ((float2*)base)[idx] = v;
}
static __device__ __forceinline__ void st2(unsigned short* base, int idx, float2 v) {
    ((unsigned int*)base)[idx] = pk2(v.x, v.y);
}

// ---------------- utility ----------------

__global__ void k_init(int* __restrict__ dstCnt, int* __restrict__ srcCnt,
                       const int* __restrict__ ids, float* __restrict__ outid, int nid) {
    int i = blockIdx.x * blockDim.x + threadIdx.x;
    if (i < NPART) { dstCnt[i] = 0; srcCnt[i] = 0; }
    if (i < nid) outid[i] = (float)ids[i];
}

// ---------------- partitioned build ----------------

// phase 1a: per-tile LDS histograms -> NPART hot global atomics per tile
__global__ void k_count(const int* __restrict__ src, const int* __restrict__ dst,
                        int* __restrict__ dstCnt, int* __restrict__ srcCnt, int E) {
    __shared__ int dh[NPART];
    __shared__ int sh2[NPART];
    const int tid = threadIdx.x;
    const int base = blockIdx.x * TILE;
    const int end = min(base + TILE, E);
    if (tid < NPART) { dh[tid] = 0; sh2[tid] = 0; }
    __syncthreads();
    for (int j = base + tid; j < end; j += 256) {
        atomicAdd(&dh[dst[j] >> PSHIFT], 1);
        atomicAdd(&sh2[src[j] >> PSHIFT], 1);
    }
    __syncthreads();
    if (tid < NPART) {
        if (dh[tid])  atomicAdd(&dstCnt[tid], dh[tid]);
        if (sh2[tid]) atomicAdd(&srcCnt[tid], sh2[tid]);
    }
}

// phase 1b: exclusive scan of NPART partition counts (256-wide block scan)
__global__ void k_scan_parts(const int* __restrict__ dstCnt, const int* __restrict__ srcCnt,
                             int* __restrict__ partBaseD, int* __restrict__ partBaseS,
                             int* __restrict__ dstCur, int* __restrict__ srcCur) {
    __shared__ int sb[256];
    const int tid = threadIdx.x;
    // dst
    int v = (tid < NPART) ? dstCnt[tid] : 0;
    sb[tid] = v;
    __syncthreads();
    for (int off = 1; off < 256; off <<= 1) {
        int x = (tid >= off) ? sb[tid - off] : 0;
        __syncthreads();
        sb[tid] += x;
        __syncthreads();
    }
    int inc = sb[tid];
    if (tid < NPART) {
        partBaseD[tid] = inc - v;
        dstCur[tid]    = inc - v;
        if (tid == NPART - 1) partBaseD[NPART] = inc;
    }
    __syncthreads();
    // src
    int v2 = (tid < NPART) ? srcCnt[tid] : 0;
    sb[tid] = v2;
    __syncthreads();
    for (int off = 1; off < 256; off <<= 1) {
        int x = (tid >= off) ? sb[tid - off] : 0;
        __syncthreads();
        sb[tid] += x;
        __syncthreads();
    }
    int inc2 = sb[tid];
    if (tid < NPART) {
        partBaseS[tid] = inc2 - v2;
        srcCur[tid]    = inc2 - v2;
        if (tid == NPART - 1) partBaseS[NPART] = inc2;
    }
}

// phase 1c: per-tile LDS scatter into bin-contiguous staging, coalesced run flush.
__global__ void k_binscatter(const int* __restrict__ src, const int* __restrict__ dst,
                             int* __restrict__ dstCur, int* __restrict__ srcCur,
                             unsigned int* __restrict__ dstStream,
                             unsigned short* __restrict__ srcStream, int E) {
    __shared__ unsigned int   stageD[TILE];    // 32 KB
    __shared__ unsigned short stageS[TILE];    // 16 KB
    __shared__ int dh[NPART], sh2[NPART];
    __shared__ int dLoc[NPART], sLoc[NPART];
    __shared__ int dBase[NPART], sBase[NPART];
    __shared__ int dFence[NPART + 1], sFence[NPART + 1];
    __shared__ int dcur[NPART], scur[NPART];
    __shared__ int sbuf[256];

    const int tid = threadIdx.x;
    const int base = blockIdx.x * TILE;
    const int end = min(base + TILE, E);
    const int n = end - base;

    if (tid < NPART) { dh[tid] = 0; sh2[tid] = 0; }
    __syncthreads();

    for (int j = base + tid; j < end; j += 256) {
        atomicAdd(&dh[dst[j] >> PSHIFT], 1);
        atomicAdd(&sh2[src[j] >> PSHIFT], 1);
    }
    __syncthreads();

    // dst scan + global run reservation
    {
        int v = (tid < NPART) ? dh[tid] : 0;
        sbuf[tid] = v;
        __syncthreads();
        for (int off = 1; off < 256; off <<= 1) {
            int x = (tid >= off) ? sbuf[tid - off] : 0;
            __syncthreads();
            sbuf[tid] += x;
            __syncthreads();
        }
        int inc = sbuf[tid];
        if (tid < NPART) {
            dLoc[tid] = inc - v;
            dcur[tid] = inc - v;
            dFence[tid + 1] = inc;
            dBase[tid] = v ? atomicAdd(&dstCur[tid], v) : 0;
        }
        if (tid == 0) dFence[0] = 0;
        __syncthreads();
    }
    // src scan + global run reservation
    {
        int v = (tid < NPART) ? sh2[tid] : 0;
        sbuf[tid] = v;
        __syncthreads();
        for (int off = 1; off < 256; off <<= 1) {
            int x = (tid >= off) ? sbuf[tid - off] : 0;
            __syncthreads();
            sbuf[tid] += x;
            __syncthreads();
        }
        int inc = sbuf[tid];
        if (tid < NPART) {
            sLoc[tid] = inc - v;
            scur[tid] = inc - v;
            sFence[tid + 1] = inc;
            sBase[tid] = v ? atomicAdd(&srcCur[tid], v) : 0;
        }
        if (tid == 0) sFence[0] = 0;
        __syncthreads();
    }

    // scatter into staging (bin-contiguous)
    for (int j = base + tid; j < end; j += 256) {
        int s = src[j], d = dst[j];
        int pd = atomicAdd(&dcur[d >> PSHIFT], 1);
        stageD[pd] = ((unsigned int)(d & (PSIZE - 1)) << SRCBITS) | (unsigned int)s;
        int ps = atomicAdd(&scur[s >> PSHIFT], 1);
        stageS[ps] = (unsigned short)(s & (PSIZE - 1));
    }
    __syncthreads();

    // flush coalesced runs
    for (int j = tid; j < n; j += 256) {
        int lo = 0, hi = NPART;
        while (hi - lo > 1) { int mid = (lo + hi) >> 1; if (dFence[mid] <= j) lo = mid; else hi = mid; }
        dstStream[dBase[lo] + (j - dLoc[lo])] = stageD[j];
        lo = 0; hi = NPART;
        while (hi - lo > 1) { int mid = (lo + hi) >> 1; if (sFence[mid] <= j) lo = mid; else hi = mid; }
        srcStream[sBase[lo] + (j - sLoc[lo])] = stageS[j];
    }
}

// phase 2a: per-dst-partition counting sort -> row_off + csr_src
__global__ void k_csr(const unsigned int* __restrict__ dstStream,
                      const int* __restrict__ partBaseD,
                      int* __restrict__ row_off, int* __restrict__ csr_src) {
    __shared__ int hist[PSIZE];   // 2 KB
    __shared__ int part[256];
    const int tid = threadIdx.x;
    const int p = blockIdx.x;
    const int nodeBase = p << PSHIFT;
    const int nN = min(PSIZE, N_NODES - nodeBase);
    const int e0 = partBaseD[p];
    const int e1 = partBaseD[p + 1];

    for (int i = tid; i < PSIZE; i += 256) hist[i] = 0;
    __syncthreads();
    for (int e = e0 + tid; e < e1; e += 256)
        atomicAdd(&hist[dstStream[e] >> SRCBITS], 1);
    __syncthreads();

    // block scan of 512: 2/thread + 256-wide block scan
    const int bi = tid * 2;
    int c0 = hist[bi], c1 = hist[bi + 1];
    part[tid] = c0 + c1;
    __syncthreads();
    for (int off = 1; off < 256; off <<= 1) {
        int v = (tid >= off) ? part[tid - off] : 0;
        __syncthreads();
        part[tid] += v;
        __syncthreads();
    }
    int run = (tid == 0) ? 0 : part[tid - 1];
    hist[bi] = run;
    if (bi < nN) row_off[nodeBase + bi] = e0 + run;
    run += c0;
    hist[bi + 1] = run;
    if (bi + 1 < nN) row_off[nodeBase + bi + 1] = e0 + run;
    if (p == NPART - 1 && tid == 0) row_off[N_NODES] = e1;
    __syncthreads();

    for (int e = e0 + tid; e < e1; e += 256) {
        unsigned int rec = dstStream[e];
        int d = rec >> SRCBITS;
        int sv = rec & SRCMASK;
        int pos = atomicAdd(&hist[d], 1);
        csr_src[e0 + pos] = sv;
    }
}

// phase 2b: per-src-partition histogram -> out_deg
__global__ void k_odeg(const unsigned short* __restrict__ srcStream,
                       const int* __restrict__ partBaseS, int* __restrict__ out_deg) {
    __shared__ int hist[PSIZE];
    const int tid = threadIdx.x;
    const int p = blockIdx.x;
    const int nodeBase = p << PSHIFT;
    const int nN = min(PSIZE, N_NODES - nodeBase);
    const int e0 = partBaseS[p];
    const int e1 = partBaseS[p + 1];

    for (int i = tid; i < PSIZE; i += 256) hist[i] = 0;
    __syncthreads();
    for (int e = e0 + tid; e < e1; e += 256)
        atomicAdd(&hist[srcStream[e]], 1);
    __syncthreads();
    for (int i = tid; i < nN; i += 256) out_deg[nodeBase + i] = hist[i];
}

// ---------------- MFMA gemm ----------------
// t[node][j] = sum_k (h[node][k] * rsqrt(out_deg[node]+1)) * W[k][j]
// 64 nodes/block (4 waves, each owns 16 rows), bf16 LDS staging, mfma 16x16x32.
// Verified layouts (learn_hip m89/m91/m120): A[m=lane&15][k=(lane>>4)*8+j],
// B[k=(lane>>4)*8+j][n=lane&15], D col=lane&15 row=(lane>>4)*4+reg.
template <int FIN, typename TIN, typename TOUT>
__global__ void k_gemm_mfma(const TIN* __restrict__ h, const int* __restrict__ out_deg,
                            const float* __restrict__ W, TOUT* __restrict__ t) {
    constexpr int PITCH = FIN + 8;               // +8 elems breaks 256B-stride bank aliasing
    __shared__ unsigned short shA[64 * PITCH];   // scaled h tile, bf16
    __shared__ unsigned short shWt[64 * PITCH];  // W transposed [n][k], bf16
    __shared__ float sno[64];

    const int tid = threadIdx.x;
    const int row0 = blockIdx.x * 64;

    if (tid < 64) {
        int node = row0 + tid;
        sno[tid] = (node < N_NODES) ? rsqrtf((float)(out_deg[node] + 1)) : 0.f;
    }
    // stage W transposed (read coalesced, 8-way write conflict only during staging)
    for (int idx = tid; idx < FIN * 64; idx += 256) {
        int k = idx >> 6;
        int nn = idx & 63;
        shWt[nn * PITCH + k] = f2bf(W[idx]);
    }
    __syncthreads();
    // stage A scaled by out_norm
    for (int idx = tid; idx < 64 * FIN; idx += 256) {
        int r = idx / FIN;
        int c = idx % FIN;
        int node = row0 + r;
        float v = (node < N_NODES) ? ldf(&h[(size_t)node * FIN + c]) * sno[r] : 0.f;
        shA[r * PITCH + c] = f2bf(v);
    }
    __syncthreads();

    const int wv = tid >> 6;
    const int lane = tid & 63;
    const int m = lane & 15;
    const int q = lane >> 4;

    f32x4 acc[4];
#pragma unroll
    for (int i = 0; i < 4; i++) acc[i] = (f32x4){0.f, 0.f, 0.f, 0.f};

    const unsigned short* Arow = &shA[(wv * 16 + m) * PITCH];
#pragma unroll
    for (int kc = 0; kc < FIN / 32; kc++) {
        int kb = kc * 32 + q * 8;
        bf16x8 a = *(const bf16x8*)&Arow[kb];
#pragma unroll
        for (int nt = 0; nt < 4; nt++) {
            bf16x8 b = *(const bf16x8*)&shWt[(nt * 16 + m) * PITCH + kb];
            acc[nt] = __builtin_amdgcn_mfma_f32_16x16x32_bf16(a, b, acc[nt], 0, 0, 0);
        }
    }

#pragma unroll
    for (int nt = 0; nt < 4; nt++) {
#pragma unroll
        for (int i = 0; i < 4; i++) {
            int node = row0 + wv * 16 + q * 4 + i;
            if (node < N_NODES) stf(&t[(size_t)node * FOUT + nt * 16 + m], acc[nt][i]);
        }
    }
}

// ---------------- CSR SpMM, bf16 rows: one wave per dst node, 2 rows/wave-load ----------------
template <typename TOUT>
__global__ void k_spmm_b(const unsigned int* __restrict__ t2,  // bf16x2 rows, pitch 32
                         const int* __restrict__ row_off, const int* __restrict__ csr_src,
                         const float* __restrict__ bias, TOUT* __restrict__ out) {
    const int wave = blockIdx.x * (blockDim.x >> 6) + (threadIdx.x >> 6);
    const int lane = threadIdx.x & 63;
    const int pair = lane >> 5;
    const int c    = lane & 31;
    const int d = wave;
    const int e0 = row_off[d];
    const int deg = row_off[d + 1] - e0;
    const float inorm = rsqrtf((float)(deg + 1));
    const int* bk = csr_src + e0;

    float2 a0 = {0.f, 0.f}, a1 = {0.f, 0.f}, a2 = {0.f, 0.f}, a3 = {0.f, 0.f};
    float2 a4 = {0.f, 0.f}, a5 = {0.f, 0.f}, a6 = {0.f, 0.f}, a7 = {0.f, 0.f};

    if (pair == 0) {
        float2 v = up2(t2[(size_t)d * 32 + c]);
        a0.x += v.x; a0.y += v.y;
    }

    int e = 0;
    for (; e + 16 <= deg; e += 16) {
        int s0 = bk[e + 0  + pair], s1 = bk[e + 2  + pair];
        int s2 = bk[e + 4  + pair], s3 = bk[e + 6  + pair];
        int s4 = bk[e + 8  + pair], s5 = bk[e + 10 + pair];
        int s6 = bk[e + 12 + pair], s7 = bk[e + 14 + pair];
        unsigned int v0 = t2[(size_t)s0 * 32 + c];
        unsigned int v1 = t2[(size_t)s1 * 32 + c];
        unsigned int v2 = t2[(size_t)s2 * 32 + c];
        unsigned int v3 = t2[(size_t)s3 * 32 + c];
        unsigned int v4 = t2[(size_t)s4 * 32 + c];
        unsigned int v5 = t2[(size_t)s5 * 32 + c];
        unsigned int v6 = t2[(size_t)s6 * 32 + c];
        unsigned int v7 = t2[(size_t)s7 * 32 + c];
        float2 f;
        f = up2(v0); a0.x += f.x; a0.y += f.y;
        f = up2(v1); a1.x += f.x; a1.y += f.y;
        f = up2(v2); a2.x += f.x; a2.y += f.y;
        f = up2(v3); a3.x += f.x; a3.y += f.y;
        f = up2(v4); a4.x += f.x; a4.y += f.y;
        f = up2(v5); a5.x += f.x; a5.y += f.y;
        f = up2(v6); a6.x += f.x; a6.y += f.y;
        f = up2(v7); a7.x += f.x; a7.y += f.y;
    }
    for (; e + 8 <= deg; e += 8) {
        int s0 = bk[e + 0 + pair], s1 = bk[e + 2 + pair];
        int s2 = bk[e + 4 + pair], s3 = bk[e + 6 + pair];
        unsigned int v0 = t2[(size_t)s0 * 32 + c];
        unsigned int v1 = t2[(size_t)s1 * 32 + c];
        unsigned int v2 = t2[(size_t)s2 * 32 + c];
        unsigned int v3 = t2[(size_t)s3 * 32 + c];
        float2 f;
        f = up2(v0); a0.x += f.x; a0.y += f.y;
        f = up2(v1); a1.x += f.x; a1.y += f.y;
        f = up2(v2); a2.x += f.x; a2.y += f.y;
        f = up2(v3); a3.x += f.x; a3.y += f.y;
    }
    for (; e + 4 <= deg; e += 4) {
        int s0 = bk[e + 0 + pair], s1 = bk[e + 2 + pair];
        unsigned int v0 = t2[(size_t)s0 * 32 + c];
        unsigned int v1 = t2[(size_t)s1 * 32 + c];
        float2 f;
        f = up2(v0); a0.x += f.x; a0.y += f.y;
        f = up2(v1); a1.x += f.x; a1.y += f.y;
    }
    for (; e + 2 <= deg; e += 2) {
        int s0 = bk[e + pair];
        float2 f = up2(t2[(size_t)s0 * 32 + c]);
        a0.x += f.x; a0.y += f.y;
    }
    if (e < deg && pair == 0) {
        float2 f = up2(t2[(size_t)bk[e] * 32 + c]);
        a0.x += f.x; a0.y += f.y;
    }

    float2 tot;
    tot.x = ((a0.x + a1.x) + (a2.x + a3.x)) + ((a4.x + a5.x) + (a6.x + a7.x));
    tot.y = ((a0.y + a1.y) + (a2.y + a3.y)) + ((a4.y + a5.y) + (a6.y + a7.y));
    tot.x += __shfl_xor(tot.x, 32);
    tot.y += __shfl_xor(tot.y, 32);

    if (pair == 0) {
        float2 bb = *(const float2*)(bias + 2 * c);
        float2 r;
        r.x = inorm * tot.x + bb.x;
        r.y = inorm * tot.y + bb.y;
        st2(out, (int)((size_t)d * 32 + c), r);
    }
}

// ---------------- fallback path (fp32, atomic CSR build) ----------------

__global__ void k_init_fb(int* __restrict__ a, int* __restrict__ b,
                          const int* __restrict__ ids, float* __restrict__ outid,
                          int n, int nid) {
    int i = blockIdx.x * blockDim.x + threadIdx.x;
    if (i < n) { a[i] = 0; b[i] = 0; }
    if (i < nid) outid[i] = (float)ids[i];
}

__global__ void k_histo(const int* __restrict__ src, const int* __restrict__ dst,
                        int* __restrict__ out_deg, int* __restrict__ in_deg, int n) {
    int i = blockIdx.x * blockDim.x + threadIdx.x;
    if (i < n) {
        atomicAdd(&out_deg[src[i]], 1);
        atomicAdd(&in_deg[dst[i]], 1);
    }
}

__global__ void k_scan_partial(const int* __restrict__ deg, int* __restrict__ block_sums, int n) {
    __shared__ int red[SCAN_BLOCK];
    const int t = threadIdx.x;
    const int base = blockIdx.x * SCAN_ELEMS + t * SCAN_ITEMS;
    int s = 0;
#pragma unroll
    for (int k = 0; k < SCAN_ITEMS; k++) {
        int i = base + k;
        if (i < n) s += deg[i];
    }
    red[t] = s;
    __syncthreads();
    for (int off = SCAN_BLOCK / 2; off > 0; off >>= 1) {
        if (t < off) red[t] += red[t + off];
        __syncthreads();
    }
    if (t == 0) block_sums[blockIdx.x] = red[0];
}

__global__ void k_scan_blocks(int* __restrict__ block_sums, int nb) {
    __shared__ int sh[SCAN_BLOCK];
    const int t = threadIdx.x;
    sh[t] = (t < nb) ? block_sums[t] : 0;
    __syncthreads();
    for (int off = 1; off < SCAN_BLOCK; off <<= 1) {
        int v = (t >= off) ? sh[t - off] : 0;
        __syncthreads();
        sh[t] += v;
        __syncthreads();
    }
    if (t < nb) block_sums[t] = (t == 0) ? 0 : sh[t - 1];
}

__global__ void k_scan_write(const int* __restrict__ deg, const int* __restrict__ block_off,
                             int* __restrict__ row_off, int* __restrict__ cursor, int n) {
    __shared__ int sh[SCAN_BLOCK];
    const int t = threadIdx.x;
    const int base = blockIdx.x * SCAN_ELEMS + t * SCAN_ITEMS;
    int v[SCAN_ITEMS];
    int s = 0;
#pragma unroll
    for (int k = 0; k < SCAN_ITEMS; k++) {
        int i = base + k;
        v[k] = (i < n) ? deg[i] : 0;
        s += v[k];
    }
    sh[t] = s;
    __syncthreads();
    for (int off = 1; off < SCAN_BLOCK; off <<= 1) {
        int x = (t >= off) ? sh[t - off] : 0;
        __syncthreads();
        sh[t] += x;
        __syncthreads();
    }
    int run = block_off[blockIdx.x] + ((t == 0) ? 0 : sh[t - 1]);
#pragma unroll
    for (int k = 0; k < SCAN_ITEMS; k++) {
        int i = base + k;
        if (i < n) { row_off[i] = run; cursor[i] = run; run += v[k]; }
    }
    if (blockIdx.x == gridDim.x - 1 && t == SCAN_BLOCK - 1) {
        row_off[n] = block_off[blockIdx.x] + sh[SCAN_BLOCK - 1];
    }
}

__global__ void k_scatter(const int* __restrict__ src, const int* __restrict__ dst,
                          int* __restrict__ cursor, int* __restrict__ csr_src, int n) {
    int i = blockIdx.x * blockDim.x + threadIdx.x;
    if (i < n) {
        int d = dst[i];
        int pos = atomicAdd(&cursor[d], 1);
        csr_src[pos] = src[i];
    }
}

template <int FIN>
__global__ void k_gemm_fb(const float* __restrict__ h, const int* __restrict__ out_deg,
                          const float* __restrict__ W, float* __restrict__ t) {
    __shared__ float sh[32 * FIN];
    __shared__ float sno[32];
    const int tid = threadIdx.x;
    const int block0 = blockIdx.x * 32;

    if (tid < 32) sno[tid] = rsqrtf((float)(out_deg[block0 + tid] + 1));
    __syncthreads();

    for (int idx = tid; idx < 32 * FIN; idx += 256) {
        int r = idx / FIN;
        int c = idx % FIN;
        sh[idx] = h[(size_t)(block0 + r) * FIN + c] * sno[r];
    }
    __syncthreads();

    const int j2 = tid & 31;
    const int rg = tid >> 5;
    const float2* W2 = (const float2*)W;
    float2 a0 = {0.f, 0.f}, a1 = {0.f, 0.f}, a2 = {0.f, 0.f}, a3 = {0.f, 0.f};
#pragma unroll 4
    for (int k = 0; k < FIN; k++) {
        float2 w = W2[k * 32 + j2];
        float s0 = sh[(rg + 0)  * FIN + k];
        float s1 = sh[(rg + 8)  * FIN + k];
        float s2 = sh[(rg + 16) * FIN + k];
        float s3 = sh[(rg + 24) * FIN + k];
        a0.x += s0 * w.x; a0.y += s0 * w.y;
        a1.x += s1 * w.x; a1.y += s1 * w.y;
        a2.x += s2 * w.x; a2.y += s2 * w.y;
        a3.x += s3 * w.x; a3.y += s3 * w.y;
    }
    float* tp = t + (size_t)block0 * FOUT;
    st2(tp, (rg + 0)  * 32 + j2, a0);
    st2(tp, (rg + 8)  * 32 + j2, a1);
    st2(tp, (rg + 16) * 32 + j2, a2);
    st2(tp, (rg + 24) * 32 + j2, a3);
}

__global__ void k_spmm_c(const float* __restrict__ t, const int* __restrict__ row_off,
                         const int* __restrict__ csr_src, const float* __restrict__ bias,
                         float* __restrict__ out) {
    const int wave = blockIdx.x * (blockDim.x >> 6) + (threadIdx.x >> 6);
    const int lane = threadIdx.x & 63;
    const int d = wave;
    const int e0 = row_off[d];
    const int e1 = row_off[d + 1];
    const float inorm = rsqrtf((float)(e1 - e0 + 1));

    float a0 = t[(size_t)d * FOUT + lane];
    float a1 = 0.f, a2 = 0.f, a3 = 0.f, a4 = 0.f, a5 = 0.f, a6 = 0.f, a7 = 0.f;
    int e = e0;
    for (; e + 8 <= e1; e += 8) {
        int s0 = csr_src[e + 0], s1 = csr_src[e + 1], s2 = csr_src[e + 2], s3 = csr_src[e + 3];
        int s4 = csr_src[e + 4], s5 = csr_src[e + 5], s6 = csr_src[e + 6], s7 = csr_src[e + 7];
        a0 += t[(size_t)s0 * FOUT + lane];
        a1 += t[(size_t)s1 * FOUT + lane];
        a2 += t[(size_t)s2 * FOUT + lane];
        a3 += t[(size_t)s3 * FOUT + lane];
        a4 += t[(size_t)s4 * FOUT + lane];
        a5 += t[(size_t)s5 * FOUT + lane];
        a6 += t[(size_t)s6 * FOUT + lane];
        a7 += t[(size_t)s7 * FOUT + lane];
    }
    for (; e + 4 <= e1; e += 4) {
        int s0 = csr_src[e + 0], s1 = csr_src[e + 1], s2 = csr_src[e + 2], s3 = csr_src[e + 3];
        a0 += t[(size_t)s0 * FOUT + lane];
        a1 += t[(size_t)s1 * FOUT + lane];
        a2 += t[(size_t)s2 * FOUT + lane];
        a3 += t[(size_t)s3 * FOUT + lane];
    }
    for (; e < e1; e++) a0 += t[(size_t)csr_src[e] * FOUT + lane];

    float acc = ((a0 + a1) + (a2 + a3)) + ((a4 + a5) + (a6 + a7));
    out[(size_t)d * FOUT + lane] = inorm * acc + bias[lane];
}

// ---------------- launch ----------------

extern "C" void kernel_launch(void* const* d_in, const int* in_sizes, int n_in,
                              void* d_out, int out_size, void* d_ws, size_t ws_size,
                              hipStream_t stream) {
    const float* h   = (const float*)d_in[0];
    const int*   src = (const int*)d_in[1];
    const int*   dst = (const int*)d_in[2];
    const int*   ids = (const int*)d_in[3];
    const float* W0  = (const float*)d_in[4];
    const float* b0  = (const float*)d_in[5];
    const float* W1  = (const float*)d_in[6];
    const float* b1  = (const float*)d_in[7];
    const float* W2  = (const float*)d_in[8];
    const float* b2  = (const float*)d_in[9];
    const int N = N_NODES;
    const int E = in_sizes[1];

    size_t o = 0;
    auto alloc = [&](size_t nbytes) -> void* {
        void* p = (char*)d_ws + o;
        o += (nbytes + 255) & ~(size_t)255;
        return p;
    };

    float* outp = (float*)d_out;
    const int B = 256;
    const int spmmGrid = N / 4;            // 25000 blocks x 4 waves
    const int mfmaGrid = (N + 63) / 64;    // 1563

    const size_t needNew =
        (((size_t)E * 4 + 255) & ~(size_t)255) +
        (((size_t)E * 2 + 255) & ~(size_t)255) +
        (((size_t)E * 4 + 255) & ~(size_t)255) +
        (((size_t)(N + 1) * 4 + 255) & ~(size_t)255) +
        (((size_t)N * 4 + 255) & ~(size_t)255) +
        6 * 1024 +
        2 * (((size_t)N * FOUT * 2 + 255) & ~(size_t)255) + 4096;

    if (ws_size >= needNew) {
        // ---------- partitioned-sort build + MFMA gemm + bf16 spmm ----------
        unsigned int*   dstStream = (unsigned int*)alloc((size_t)E * 4);
        unsigned short* srcStream = (unsigned short*)alloc((size_t)E * 2);
        int*            csr_src   = (int*)alloc((size_t)E * 4);
        int*            row_off   = (int*)alloc((size_t)(N + 1) * 4);
        int*            out_deg   = (int*)alloc((size_t)N * 4);
        int*            dstCnt    = (int*)alloc(1024);
        int*            srcCnt    = (int*)alloc(1024);
        int*            dstCur    = (int*)alloc(1024);
        int*            srcCur    = (int*)alloc(1024);
        int*            partBaseD = (int*)alloc(1024);
        int*            partBaseS = (int*)alloc(1024);
        unsigned short* t         = (unsigned short*)alloc((size_t)N * FOUT * 2);
        unsigned short* hbuf      = (unsigned short*)alloc((size_t)N * FOUT * 2);

        const int nTiles = (E + TILE - 1) / TILE;   // 196

        k_init<<<4, B, 0, stream>>>(dstCnt, srcCnt, ids, outp + (size_t)N * FOUT, 1024);
        k_count<<<nTiles, B, 0, stream>>>(src, dst, dstCnt, srcCnt, E);
        k_scan_parts<<<1, 256, 0, stream>>>(dstCnt, srcCnt, partBaseD, partBaseS, dstCur, srcCur);
        k_binscatter<<<nTiles, B, 0, stream>>>(src, dst, dstCur, srcCur, dstStream, srcStream, E);
        k_csr<<<NPART, B, 0, stream>>>(dstStream, partBaseD, row_off, csr_src);
        k_odeg<<<NPART, B, 0, stream>>>(srcStream, partBaseS, out_deg);

        // layer 0: 128 -> 64 (fp32 in, bf16 out)
        k_gemm_mfma<128, float, unsigned short><<<mfmaGrid, 256, 0, stream>>>(h, out_deg, W0, t);
        k_spmm_b<unsigned short><<<spmmGrid, 256, 0, stream>>>((const unsigned int*)t, row_off, csr_src, b0, hbuf);
        // layer 1
        k_gemm_mfma<64, unsigned short, unsigned short><<<mfmaGrid, 256, 0, stream>>>(hbuf, out_deg, W1, t);
        k_spmm_b<unsigned short><<<spmmGrid, 256, 0, stream>>>((const unsigned int*)t, row_off, csr_src, b1, hbuf);
        // layer 2 (fp32 final out)
        k_gemm_mfma<64, unsigned short, unsigned short><<<mfmaGrid, 256, 0, stream>>>(hbuf, out_deg, W2, t);
        k_spmm_b<float><<<spmmGrid, 256, 0, stream>>>((const unsigned int*)t, row_off, csr_src, b2, outp);
    } else {
        // ---------- CSR fallback (fp32, atomic build) ----------
        int*   in_deg  = (int*)alloc((size_t)N * 4);
        int*   out_deg = (int*)alloc((size_t)N * 4);
        int*   row_off = (int*)alloc((size_t)(N + 1) * 4);
        int*   cursor  = (int*)alloc((size_t)N * 4);
        int*   csr_src = (int*)alloc((size_t)E * 4);
        float* t       = (float*)alloc((size_t)N * FOUT * 4);
        float* hbuf    = (float*)alloc((size_t)N * FOUT * 4);
        int*   bsums   = (int*)alloc((size_t)SCAN_BLOCK * 4);

        const int gN = (N + B - 1) / B;
        const int gE = (E + B - 1) / B;
        const int nScanBlocks = (N + SCAN_ELEMS - 1) / SCAN_ELEMS;

        k_init_fb<<<gN, B, 0, stream>>>(in_deg, out_deg, ids, outp + (size_t)N * FOUT, N, 1024);
        k_histo<<<gE, B, 0, stream>>>(src, dst, out_deg, in_deg, E);
        k_scan_partial<<<nScanBlocks, SCAN_BLOCK, 0, stream>>>(in_deg, bsums, N);
        k_scan_blocks<<<1, SCAN_BLOCK, 0, stream>>>(bsums, nScanBlocks);
        k_scan_write<<<nScanBlocks, SCAN_BLOCK, 0, stream>>>(in_deg, bsums, row_off, cursor, N);
        k_scatter<<<gE, B, 0, stream>>>(src, dst, cursor, csr_src, E);

        k_gemm_fb<128><<<N / 32, 256, 0, stream>>>(h, out_deg, W0, t);
        k_spmm_c<<<spmmGrid, 256, 0, stream>>>(t, row_off, csr_src, b0, hbuf);
        k_gemm_fb<64><<<N / 32, 256, 0, stream>>>(hbuf, out_deg, W1, t);
        k_spmm_c<<<spmmGrid, 256, 0, stream>>>(t, row_off, csr_src, b1, hbuf);
        k_gemm_fb<64><<<N / 32, 256, 0, stream>>>(hbuf, out_deg, W2, t);
        k_spmm_c<<<spmmGrid, 256, 0, stream>>>(t, row_off, csr_src, b2, outp);
    }
}